// Round 17
// baseline (141.938 us; speedup 1.0000x reference)
//
#include <hip/hip_runtime.h>

// LR_PINN_phase2_midout: fused 4-stage tiny MLP, N=262144, H=256, R=32.
// R17 = R16 + two VALU->matrix-pipe offloads (R12-vs-R16 lesson: only VALU
// issue-cycle cuts pay; MFMA pipe co-issues across waves and has headroom):
//  (1) phase0 as MFMA: z = S(x*w0+t*w1+b) as one K=16 MFMA/stream/tile;
//      A = w-frags (k0,1=S*w0, k2,3=S*w1, k4=S*b), B = {x_hi,x_lo,t_hi,t_lo,1}
//      (fp16 hi/lo split of x,t -> error ~1e-6). Deletes 512 fma + 48 b128
//      loads per quad-iter.
//  (2) epilogue dot as MFMA: A-frag rows all = -2*ew; 16 accumulated tiles
//      leave the full dot in every lane's .x -> deletes 256 fma + the final
//      shuffle reduce (inv packed fp16 in the dot: +~2e-4 absmax, 2x margin).
//
// Kept from R16: all-LDS weights (1 block/CU, 4 waves/SIMD), quad streams,
// inv-feeding (inv=rcp(exp2(y)+1), -2 folded into ctf/ew-frags, rowsum accs),
// mfma_f32_16x16x16f16 layout-closed chain, fragment-ordered conflict-free
// LDS (base+lane*8), unroll-1 t-loops, v_cvt_pkrtz packing.

typedef _Float16 half4_t __attribute__((ext_vector_type(4)));
typedef __fp16   fp16x2  __attribute__((ext_vector_type(2)));
typedef float    float4_t __attribute__((ext_vector_type(4)));

#define TANH_SCALE 2.885390081777927f  // 2*log2(e); exp2(S*x) == exp(2x)
#define MFMA16 __builtin_amdgcn_mfma_f32_16x16x16f16

namespace {

struct alignas(16) Smem {
  // frag entry e = ((k*16+t)*2+sel)*64+lane ; one half4 (8 B) per lane.
  half4_t ctf[3 * 16 * 2 * 64];  // 48 KB: -2*alpha*Ct[sel*16+m][16t+4q+jj]
  half4_t rwf[3 * 16 * 2 * 64];  // 48 KB:  S * R[16t+m][sel*16+4q+jj]
  half4_t wff[16 * 64];          //  8 KB: phase0 A-frags (S*w0/S*w1/S*b by k)
  half4_t ewf[16 * 64];          //  8 KB: epilogue A-frags (-2*ew, row-const)
  float rsC[3 * 32];             // rowsums: sum_j alpha*Ct[r][j]
};

__device__ __forceinline__ half4_t pack4(float4_t v) {
  union { fp16x2 f2[2]; half4_t h4; } u;
  u.f2[0] = __builtin_amdgcn_cvt_pkrtz(v.x, v.y);
  u.f2[1] = __builtin_amdgcn_cvt_pkrtz(v.z, v.w);
  return u.h4;
}

// inv = 1/(1+exp2(y)); tanh(x) = 1 - 2*inv (the -2/+1 live in weights/sums).
__device__ __forceinline__ float inv_pre(float y) {
  return __builtin_amdgcn_rcpf(__builtin_amdgcn_exp2f(y) + 1.0f);
}

__device__ __forceinline__ half4_t inv4(float4_t v) {
  float4_t r;
  r.x = inv_pre(v.x); r.y = inv_pre(v.y);
  r.z = inv_pre(v.z); r.w = inv_pre(v.w);
  return pack4(r);
}

__global__ __launch_bounds__(1024)
__attribute__((amdgpu_waves_per_eu(4, 4)))
void pinn_fused(
    const float* __restrict__ xg, const float* __restrict__ tg,
    const float* __restrict__ sw, const float* __restrict__ sb,
    const float* __restrict__ ewp, const float* __restrict__ ebp,
    const float* __restrict__ c0, const float* __restrict__ c1,
    const float* __restrict__ c2, const float* __restrict__ r0,
    const float* __restrict__ r1, const float* __restrict__ r2,
    const float* __restrict__ a0, const float* __restrict__ a1,
    const float* __restrict__ a2, float* __restrict__ out, int n)
{
  __shared__ Smem sm;
  const int tid = threadIdx.x;

  // ---- stage ctf / rwf (fragment-ordered fp16, folds: -2*alpha, S) ----
  for (int e = tid; e < 3 * 16 * 2 * 64; e += 1024) {
    const int lane_ = e & 63;
    const int sel   = (e >> 6) & 1;
    const int t_    = (e >> 7) & 15;
    const int k_    = e >> 11;
    const int m_ = lane_ & 15, q_ = lane_ >> 4;
    const float* ck = (k_ == 0) ? c0 : (k_ == 1) ? c1 : c2;
    const float* rk = (k_ == 0) ? r0 : (k_ == 1) ? r1 : r2;
    const float* ak = (k_ == 0) ? a0 : (k_ == 1) ? a1 : a2;
    {
      const int r = sel * 16 + m_;
      const float av = ak[r] * -2.0f;
      const int j0 = 16 * t_ + 4 * q_;
      half4_t v;
      v.x = (_Float16)(ck[(j0 + 0) * 32 + r] * av);
      v.y = (_Float16)(ck[(j0 + 1) * 32 + r] * av);
      v.z = (_Float16)(ck[(j0 + 2) * 32 + r] * av);
      v.w = (_Float16)(ck[(j0 + 3) * 32 + r] * av);
      sm.ctf[e] = v;
    }
    {
      const int j = 16 * t_ + m_;
      const int rr = sel * 16 + 4 * q_;
      half4_t v;
      v.x = (_Float16)(rk[j * 32 + rr + 0] * TANH_SCALE);
      v.y = (_Float16)(rk[j * 32 + rr + 1] * TANH_SCALE);
      v.z = (_Float16)(rk[j * 32 + rr + 2] * TANH_SCALE);
      v.w = (_Float16)(rk[j * 32 + rr + 3] * TANH_SCALE);
      sm.rwf[e] = v;
    }
  }
  {  // wff: A[row=j-in-tile][k]: k0,1=S*w0[j]; k2,3=S*w1[j]; k4=S*b[j]; else 0
    const int t_ = tid >> 6, lane_ = tid & 63;
    const int m_ = lane_ & 15, q_ = lane_ >> 4;
    const int j = 16 * t_ + m_;
    half4_t v = {(_Float16)0.f, (_Float16)0.f, (_Float16)0.f, (_Float16)0.f};
    if (q_ == 0) {
      const float w0v = sw[2 * j] * TANH_SCALE;
      const float w1v = sw[2 * j + 1] * TANH_SCALE;
      v.x = (_Float16)w0v; v.y = (_Float16)w0v;
      v.z = (_Float16)w1v; v.w = (_Float16)w1v;
    } else if (q_ == 1) {
      v.x = (_Float16)(sb[j] * TANH_SCALE);
    }
    sm.wff[tid] = v;
    // ewf: A[*][k] = -2*ew[16t+k] (row-independent)
    const int j0 = 16 * t_ + 4 * q_;
    half4_t w;
    w.x = (_Float16)(ewp[j0 + 0] * -2.0f);
    w.y = (_Float16)(ewp[j0 + 1] * -2.0f);
    w.z = (_Float16)(ewp[j0 + 2] * -2.0f);
    w.w = (_Float16)(ewp[j0 + 3] * -2.0f);
    sm.ewf[tid] = w;
  }
  __syncthreads();

  // ---- rowsums rsC[k][r] = sum_j alpha*Ct[r][j] = -0.5 * sum(ctf frags) ----
  if (tid < 96) {
    const int k_ = tid >> 5, r = tid & 31;
    const int sel = r >> 4, mm = r & 15;
    float s = 0.0f;
    for (int t = 0; t < 16; ++t)
      for (int qq = 0; qq < 4; ++qq) {
        const half4_t v = sm.ctf[((k_ * 16 + t) * 2 + sel) * 64 + 16 * qq + mm];
        s += (float)v.x + (float)v.y + (float)v.z + (float)v.w;
      }
    sm.rsC[k_ * 32 + r] = -0.5f * s;
  }
  __syncthreads();

  const int wave = tid >> 6;
  const int lane = tid & 63;
  const int m = lane & 15;   // point index (MFMA col / A-row / B-col)
  const int q = lane >> 4;   // quad
  const int wo = 4 * q;
  const float ebv = ebp[0];
  const int tiles = n >> 4;

  // ewc = sum_j ew[j] (full, all lanes): from ewf (= -2*ew), 2 shuffles once
  float ewc;
  {
    float s = 0.0f;
    for (int t = 0; t < 16; ++t) {
      const half4_t e4 = sm.ewf[t * 64 + lane];
      s += (float)e4.x + (float)e4.y + (float)e4.z + (float)e4.w;
    }
    s += __shfl_xor(s, 16);
    s += __shfl_xor(s, 32);
    ewc = -0.5f * s;
  }

  const float4_t z4 = {0.f, 0.f, 0.f, 0.f};

#pragma unroll 1
  for (int g = (blockIdx.x * 16 + wave) * 4; g < tiles; g += 16384) {
    // per-stream phase0 B-frags: {x_hi, x_lo, t_hi, t_lo} (q0), {1,0,0,0} (q1)
    half4_t bs[4];
#pragma unroll
    for (int s = 0; s < 4; ++s) {
      const float xv = xg[(g + s) * 16 + m];
      const float tv = tg[(g + s) * 16 + m];
      const _Float16 xh = (_Float16)xv;
      const _Float16 xl = (_Float16)(xv - (float)xh);
      const _Float16 th = (_Float16)tv;
      const _Float16 tl = (_Float16)(tv - (float)th);
      const half4_t b0 = {xh, xl, th, tl};
      const half4_t b1 = {(_Float16)1.0f, (_Float16)0.f, (_Float16)0.f, (_Float16)0.f};
      const half4_t bz = {(_Float16)0.f, (_Float16)0.f, (_Float16)0.f, (_Float16)0.f};
      bs[s] = (q == 0) ? b0 : ((q == 1) ? b1 : bz);
    }

    // ---- phase0 (z via MFMA) fused with GEMM1(k=0); accs init rowsums(0) ----
    const float4_t rs00 = *(const float4_t*)&sm.rsC[wo];
    const float4_t rs01 = *(const float4_t*)&sm.rsC[16 + wo];
    float4_t acc[4][2];
#pragma unroll
    for (int s = 0; s < 4; ++s) { acc[s][0] = rs00; acc[s][1] = rs01; }
    const half4_t* wp  = &sm.wff[lane];
    const half4_t* cp0 = &sm.ctf[lane];
#pragma unroll 1
    for (int t = 0; t < 16; ++t) {
      const half4_t wA = wp[0];
      const half4_t cA = cp0[0], cB = cp0[64];
      float4_t zz[4];
#pragma unroll
      for (int s = 0; s < 4; ++s) zz[s] = MFMA16(wA, bs[s], z4, 0, 0, 0);
      half4_t h[4];
#pragma unroll
      for (int s = 0; s < 4; ++s) h[s] = inv4(zz[s]);
#pragma unroll
      for (int s = 0; s < 4; ++s) acc[s][0] = MFMA16(cA, h[s], acc[s][0], 0, 0, 0);
#pragma unroll
      for (int s = 0; s < 4; ++s) acc[s][1] = MFMA16(cB, h[s], acc[s][1], 0, 0, 0);
      wp += 64; cp0 += 128;
    }

#pragma unroll 1
    for (int k = 0; k < 2; ++k) {
      half4_t pf[4][2];
#pragma unroll
      for (int s = 0; s < 4; ++s) {
        pf[s][0] = pack4(acc[s][0]);
        pf[s][1] = pack4(acc[s][1]);
      }
      const float4_t rsA = *(const float4_t*)&sm.rsC[(k + 1) * 32 + wo];
      const float4_t rsB = *(const float4_t*)&sm.rsC[(k + 1) * 32 + 16 + wo];
      float4_t nn[4][2];
#pragma unroll
      for (int s = 0; s < 4; ++s) { nn[s][0] = rsA; nn[s][1] = rsB; }
      const half4_t* rp = &sm.rwf[k * 2048 + lane];
      const half4_t* cp = &sm.ctf[(k + 1) * 2048 + lane];
#pragma unroll 1
      for (int t = 0; t < 16; ++t) {
        const half4_t rA = rp[0], rB = rp[64];
        const half4_t cA = cp[0], cB = cp[64];
        float4_t u[4];
#pragma unroll
        for (int s = 0; s < 4; ++s) u[s] = MFMA16(rA, pf[s][0], z4, 0, 0, 0);
#pragma unroll
        for (int s = 0; s < 4; ++s) u[s] = MFMA16(rB, pf[s][1], u[s], 0, 0, 0);
        half4_t h[4];
#pragma unroll
        for (int s = 0; s < 4; ++s) h[s] = inv4(u[s]);
#pragma unroll
        for (int s = 0; s < 4; ++s) nn[s][0] = MFMA16(cA, h[s], nn[s][0], 0, 0, 0);
#pragma unroll
        for (int s = 0; s < 4; ++s) nn[s][1] = MFMA16(cB, h[s], nn[s][1], 0, 0, 0);
        rp += 128; cp += 128;
      }
#pragma unroll
      for (int s = 0; s < 4; ++s) { acc[s][0] = nn[s][0]; acc[s][1] = nn[s][1]; }
    }

    // ---- k=2: GEMM2(2) + end_w dot via MFMA (A rows all = -2*ew) ----
    float4_t ae[4];
#pragma unroll
    for (int s = 0; s < 4; ++s) ae[s] = z4;
    {
      half4_t pf[4][2];
#pragma unroll
      for (int s = 0; s < 4; ++s) {
        pf[s][0] = pack4(acc[s][0]);
        pf[s][1] = pack4(acc[s][1]);
      }
      const half4_t* rp = &sm.rwf[2 * 2048 + lane];
      const half4_t* ep = &sm.ewf[lane];
#pragma unroll 1
      for (int t = 0; t < 16; ++t) {
        const half4_t rA = rp[0], rB = rp[64];
        const half4_t eA = ep[0];
        float4_t u[4];
#pragma unroll
        for (int s = 0; s < 4; ++s) u[s] = MFMA16(rA, pf[s][0], z4, 0, 0, 0);
#pragma unroll
        for (int s = 0; s < 4; ++s) u[s] = MFMA16(rB, pf[s][1], u[s], 0, 0, 0);
        half4_t h[4];
#pragma unroll
        for (int s = 0; s < 4; ++s) h[s] = inv4(u[s]);
#pragma unroll
        for (int s = 0; s < 4; ++s) ae[s] = MFMA16(eA, h[s], ae[s], 0, 0, 0);
        rp += 128; ep += 64;
      }
    }

    // every lane's ae[s].x holds the full dot for col m (all A rows equal)
    if (lane < 16) {
#pragma unroll
      for (int s = 0; s < 4; ++s) out[(g + s) * 16 + m] = ae[s].x + ewc + ebv;
    }
  }
}

}  // namespace

extern "C" void kernel_launch(void* const* d_in, const int* in_sizes, int n_in,
                              void* d_out, int out_size, void* d_ws, size_t ws_size,
                              hipStream_t stream) {
  const float* xg  = (const float*)d_in[0];
  const float* tg  = (const float*)d_in[1];
  const float* sw  = (const float*)d_in[2];
  const float* sb  = (const float*)d_in[3];
  const float* ewp = (const float*)d_in[4];
  const float* ebp = (const float*)d_in[5];
  const float* c0  = (const float*)d_in[6];
  const float* c1  = (const float*)d_in[7];
  const float* c2  = (const float*)d_in[8];
  const float* r0  = (const float*)d_in[9];
  const float* r1  = (const float*)d_in[10];
  const float* r2  = (const float*)d_in[11];
  const float* a0  = (const float*)d_in[12];
  const float* a1  = (const float*)d_in[13];
  const float* a2  = (const float*)d_in[14];
  float* outp = (float*)d_out;

  const int n = in_sizes[0];  // 262144

  pinn_fused<<<256, 1024, 0, stream>>>(xg, tg, sw, sb, ewp, ebp,
                                       c0, c1, c2, r0, r1, r2, a0, a1, a2,
                                       outp, n);
}

// Round 18
// 140.631 us; speedup vs baseline: 1.0093x; 1.0093x over previous
//
#include <hip/hip_runtime.h>

// LR_PINN_phase2_midout: fused 4-stage tiny MLP, N=262144, H=256, R=32.
// R18 = R16 verbatim (session best: 70.5 us, absmax 7.3e-4, 2x threshold
// margin). R17's epilogue-as-MFMA was wall-neutral but pushed absmax to
// 1.46e-3 (4% margin) -> reverted.
//
// Converged design:
//  - mfma_f32_16x16x16f16 layout-closed chain: C/D layout (col=lane&15=point,
//    row=4q+reg) == next MFMA's B-frag layout (k=4q+jj) -> phase0 ->
//    (GEMM1 -> GEMM2 -> act)^3 -> dot entirely in registers; no LDS
//    round-trips, no barriers in steady state; only cross-lane op is the
//    final 2-shuffle reduce.
//  - All weights LDS-resident, fragment-ordered (every hot read =
//    base + lane*8: conflict-free by construction; SQ_LDS_BANK_CONFLICT=0).
//  - Quad point-tile streams/wave: 4 independent MFMA->act chains per
//    unroll-1 body, phase-grouped for in-order issue.
//  - inv-feeding: inv = rcp(exp2(S*x)+1) replaces tanh (saves the fma);
//    -2 folded into ctf & ew, GEMM1 accs init with rowsums, epilogue with
//    ewsum; S = 2*log2e folded into w0/w1/bb/rwf at staging.
//  - Issue-port status at this kernel: VALUBusy+MfmaUtil ~= 101% ->
//    sequencer saturated; instruction stream near-minimal (trans batching
//    regressed twice; pipe-offload neutral; ILP/TLP saturated/neutral).

typedef _Float16 half4_t __attribute__((ext_vector_type(4)));
typedef __fp16   fp16x2  __attribute__((ext_vector_type(2)));
typedef float    float4_t __attribute__((ext_vector_type(4)));

#define TANH_SCALE 2.885390081777927f  // 2*log2(e); exp2(S*x) == exp(2x)
#define MFMA16 __builtin_amdgcn_mfma_f32_16x16x16f16

namespace {

struct alignas(16) Smem {
  // entry index e = ((k*16+t)*2+sel)*64+lane ; one half4 (8 B) per lane.
  half4_t ctf[3 * 16 * 2 * 64];  // 48 KB: -2 * alpha * Ct[sel*16+m][16t+4q+jj]
  half4_t rwf[3 * 16 * 2 * 64];  // 48 KB:  S * R[16t+m][sel*16+4q+jj]
  float w0[256], w1[256], bb[256];  // pre-scaled by S
  float ew[256];                    // -2 * end_w
  float rsC[3 * 32];                // rowsums: sum_j alpha*Ct[r][j]
};

__device__ __forceinline__ half4_t pack4(float4_t v) {
  union { fp16x2 f2[2]; half4_t h4; } u;
  u.f2[0] = __builtin_amdgcn_cvt_pkrtz(v.x, v.y);
  u.f2[1] = __builtin_amdgcn_cvt_pkrtz(v.z, v.w);
  return u.h4;
}

// inv = 1/(1+exp2(y)); tanh(x) = 1 - 2*inv (the -2/+1 live in weights/sums).
// No clamp: e=inf -> rcp(inf)=0 exact; e->0 -> inv->1 exact.
__device__ __forceinline__ float inv_pre(float y) {
  return __builtin_amdgcn_rcpf(__builtin_amdgcn_exp2f(y) + 1.0f);
}

__device__ __forceinline__ half4_t inv4(float4_t v) {
  float4_t r;
  r.x = inv_pre(v.x); r.y = inv_pre(v.y);
  r.z = inv_pre(v.z); r.w = inv_pre(v.w);
  return pack4(r);
}

__global__ __launch_bounds__(1024)
__attribute__((amdgpu_waves_per_eu(4, 4)))
void pinn_fused(
    const float* __restrict__ xg, const float* __restrict__ tg,
    const float* __restrict__ sw, const float* __restrict__ sb,
    const float* __restrict__ ewp, const float* __restrict__ ebp,
    const float* __restrict__ c0, const float* __restrict__ c1,
    const float* __restrict__ c2, const float* __restrict__ r0,
    const float* __restrict__ r1, const float* __restrict__ r2,
    const float* __restrict__ a0, const float* __restrict__ a1,
    const float* __restrict__ a2, float* __restrict__ out, int n)
{
  __shared__ Smem sm;
  const int tid = threadIdx.x;

  // ---- stage weights into fragment-ordered fp16 LDS (once per block) ----
  for (int e = tid; e < 3 * 16 * 2 * 64; e += 1024) {
    const int lane_ = e & 63;
    const int sel   = (e >> 6) & 1;
    const int t_    = (e >> 7) & 15;
    const int k_    = e >> 11;
    const int m_ = lane_ & 15, q_ = lane_ >> 4;
    const float* ck = (k_ == 0) ? c0 : (k_ == 1) ? c1 : c2;
    const float* rk = (k_ == 0) ? r0 : (k_ == 1) ? r1 : r2;
    const float* ak = (k_ == 0) ? a0 : (k_ == 1) ? a1 : a2;
    {  // Ct frag: A-row r = sel*16+m, cols j = 16t+4q+jj ; fold -2*alpha
      const int r = sel * 16 + m_;
      const float av = ak[r] * -2.0f;
      const int j0 = 16 * t_ + 4 * q_;
      half4_t v;
      v.x = (_Float16)(ck[(j0 + 0) * 32 + r] * av);
      v.y = (_Float16)(ck[(j0 + 1) * 32 + r] * av);
      v.z = (_Float16)(ck[(j0 + 2) * 32 + r] * av);
      v.w = (_Float16)(ck[(j0 + 3) * 32 + r] * av);
      sm.ctf[e] = v;
    }
    {  // R frag: A-row j = 16t+m, cols r = sel*16+4q+jj ; fold tanh scale S
      const int j = 16 * t_ + m_;
      const int rr = sel * 16 + 4 * q_;
      half4_t v;
      v.x = (_Float16)(rk[j * 32 + rr + 0] * TANH_SCALE);
      v.y = (_Float16)(rk[j * 32 + rr + 1] * TANH_SCALE);
      v.z = (_Float16)(rk[j * 32 + rr + 2] * TANH_SCALE);
      v.w = (_Float16)(rk[j * 32 + rr + 3] * TANH_SCALE);
      sm.rwf[e] = v;
    }
  }
  if (tid < 256) {
    sm.w0[tid] = sw[2 * tid] * TANH_SCALE;
    sm.w1[tid] = sw[2 * tid + 1] * TANH_SCALE;
    sm.bb[tid] = sb[tid] * TANH_SCALE;
    sm.ew[tid] = ewp[tid] * -2.0f;              // fold -2
  }
  __syncthreads();

  // ---- rowsums rsC[k][r] = sum_j alpha*Ct[r][j] = -0.5 * sum(ctf frags) ----
  if (tid < 96) {
    const int k_ = tid >> 5, r = tid & 31;
    const int sel = r >> 4, mm = r & 15;
    float s = 0.0f;
    for (int t = 0; t < 16; ++t)
      for (int qq = 0; qq < 4; ++qq) {
        const half4_t v = sm.ctf[((k_ * 16 + t) * 2 + sel) * 64 + 16 * qq + mm];
        s += (float)v.x + (float)v.y + (float)v.z + (float)v.w;
      }
    sm.rsC[k_ * 32 + r] = -0.5f * s;
  }
  __syncthreads();

  const int wave = tid >> 6;
  const int lane = tid & 63;
  const int m = lane & 15;   // point index (MFMA col / A-row / B-col)
  const int q = lane >> 4;   // quad
  const int wo = 4 * q;      // j = 16t + 4q + jj
  const float ebv = ebp[0];
  const int tiles = n >> 4;

  // per-lane ewsum: out = sum(ew)+sum((-2ew)*inv); sm.ew = -2*ew
  float ewsum = 0.0f;
  for (int t = 0; t < 16; ++t) {
    const float4_t e4 = *(const float4_t*)&sm.ew[t * 16 + wo];
    ewsum += e4.x + e4.y + e4.z + e4.w;
  }
  ewsum *= -0.5f;

  const float4_t z4 = {0.f, 0.f, 0.f, 0.f};  // hoisted MFMA C-operand zero

#pragma unroll 1
  for (int g = (blockIdx.x * 16 + wave) * 4; g < tiles; g += 16384) {
    float xm[4], tm[4];
#pragma unroll
    for (int s = 0; s < 4; ++s) {
      xm[s] = xg[(g + s) * 16 + m];
      tm[s] = tg[(g + s) * 16 + m];
    }

    // ---- phase0 fused with GEMM1(k=0); 4 streams, accs init rowsums(0) ----
    const float4_t rs00 = *(const float4_t*)&sm.rsC[wo];
    const float4_t rs01 = *(const float4_t*)&sm.rsC[16 + wo];
    float4_t acc[4][2];
#pragma unroll
    for (int s = 0; s < 4; ++s) { acc[s][0] = rs00; acc[s][1] = rs01; }
    const half4_t* cp0 = &sm.ctf[lane];
#pragma unroll 1
    for (int t = 0; t < 16; ++t) {
      const int cb = t * 16 + wo;
      const float4_t w0v = *(const float4_t*)&sm.w0[cb];
      const float4_t w1v = *(const float4_t*)&sm.w1[cb];
      const float4_t bv  = *(const float4_t*)&sm.bb[cb];
      half4_t h[4];
#pragma unroll
      for (int s = 0; s < 4; ++s) {
        float4_t z;
        z.x = fmaf(xm[s], w0v.x, fmaf(tm[s], w1v.x, bv.x));
        z.y = fmaf(xm[s], w0v.y, fmaf(tm[s], w1v.y, bv.y));
        z.z = fmaf(xm[s], w0v.z, fmaf(tm[s], w1v.z, bv.z));
        z.w = fmaf(xm[s], w0v.w, fmaf(tm[s], w1v.w, bv.w));
        h[s] = inv4(z);
      }
      const half4_t cA = cp0[0], cB = cp0[64];
#pragma unroll
      for (int s = 0; s < 4; ++s) acc[s][0] = MFMA16(cA, h[s], acc[s][0], 0, 0, 0);
#pragma unroll
      for (int s = 0; s < 4; ++s) acc[s][1] = MFMA16(cB, h[s], acc[s][1], 0, 0, 0);
      cp0 += 128;
    }

#pragma unroll 1
    for (int k = 0; k < 2; ++k) {
      // acc holds true P (rowsum init); pack as next B-frag.
      half4_t pf[4][2];
#pragma unroll
      for (int s = 0; s < 4; ++s) {
        pf[s][0] = pack4(acc[s][0]);
        pf[s][1] = pack4(acc[s][1]);
      }
      const float4_t rsA = *(const float4_t*)&sm.rsC[(k + 1) * 32 + wo];
      const float4_t rsB = *(const float4_t*)&sm.rsC[(k + 1) * 32 + 16 + wo];
      float4_t nn[4][2];
#pragma unroll
      for (int s = 0; s < 4; ++s) { nn[s][0] = rsA; nn[s][1] = rsB; }
      const half4_t* rp = &sm.rwf[k * 2048 + lane];
      const half4_t* cp = &sm.ctf[(k + 1) * 2048 + lane];
#pragma unroll 1
      for (int t = 0; t < 16; ++t) {
        const half4_t rA = rp[0], rB = rp[64];
        const half4_t cA = cp[0], cB = cp[64];
        float4_t u[4];
#pragma unroll
        for (int s = 0; s < 4; ++s) u[s] = MFMA16(rA, pf[s][0], z4, 0, 0, 0);
#pragma unroll
        for (int s = 0; s < 4; ++s) u[s] = MFMA16(rB, pf[s][1], u[s], 0, 0, 0);
        half4_t h[4];
#pragma unroll
        for (int s = 0; s < 4; ++s) h[s] = inv4(u[s]);
#pragma unroll
        for (int s = 0; s < 4; ++s) nn[s][0] = MFMA16(cA, h[s], nn[s][0], 0, 0, 0);
#pragma unroll
        for (int s = 0; s < 4; ++s) nn[s][1] = MFMA16(cB, h[s], nn[s][1], 0, 0, 0);
        rp += 128; cp += 128;
      }
#pragma unroll
      for (int s = 0; s < 4; ++s) { acc[s][0] = nn[s][0]; acc[s][1] = nn[s][1]; }
    }

    // ---- k=2: GEMM2(2) fused with the end_w dot; ssum init = ewsum ----
    float ssum[4] = {ewsum, ewsum, ewsum, ewsum};
    {
      half4_t pf[4][2];
#pragma unroll
      for (int s = 0; s < 4; ++s) {
        pf[s][0] = pack4(acc[s][0]);
        pf[s][1] = pack4(acc[s][1]);
      }
      const half4_t* rp = &sm.rwf[2 * 2048 + lane];
#pragma unroll 1
      for (int t = 0; t < 16; ++t) {
        const half4_t rA = rp[0], rB = rp[64];
        const float4_t ev = *(const float4_t*)&sm.ew[t * 16 + wo];  // -2*ew
        float4_t u[4];
#pragma unroll
        for (int s = 0; s < 4; ++s) u[s] = MFMA16(rA, pf[s][0], z4, 0, 0, 0);
#pragma unroll
        for (int s = 0; s < 4; ++s) u[s] = MFMA16(rB, pf[s][1], u[s], 0, 0, 0);
#pragma unroll
        for (int s = 0; s < 4; ++s) {
          ssum[s] = fmaf(ev.x, inv_pre(u[s].x), ssum[s]);
          ssum[s] = fmaf(ev.y, inv_pre(u[s].y), ssum[s]);
          ssum[s] = fmaf(ev.z, inv_pre(u[s].z), ssum[s]);
          ssum[s] = fmaf(ev.w, inv_pre(u[s].w), ssum[s]);
        }
        rp += 128;
      }
    }

    // reduce each stream's partial dot over the 4 quads
#pragma unroll
    for (int s = 0; s < 4; ++s) {
      ssum[s] += __shfl_xor(ssum[s], 16);
      ssum[s] += __shfl_xor(ssum[s], 32);
    }
    if (lane < 16) {
#pragma unroll
      for (int s = 0; s < 4; ++s) out[(g + s) * 16 + m] = ssum[s] + ebv;
    }
  }
}

}  // namespace

extern "C" void kernel_launch(void* const* d_in, const int* in_sizes, int n_in,
                              void* d_out, int out_size, void* d_ws, size_t ws_size,
                              hipStream_t stream) {
  const float* xg  = (const float*)d_in[0];
  const float* tg  = (const float*)d_in[1];
  const float* sw  = (const float*)d_in[2];
  const float* sb  = (const float*)d_in[3];
  const float* ewp = (const float*)d_in[4];
  const float* ebp = (const float*)d_in[5];
  const float* c0  = (const float*)d_in[6];
  const float* c1  = (const float*)d_in[7];
  const float* c2  = (const float*)d_in[8];
  const float* r0  = (const float*)d_in[9];
  const float* r1  = (const float*)d_in[10];
  const float* r2  = (const float*)d_in[11];
  const float* a0  = (const float*)d_in[12];
  const float* a1  = (const float*)d_in[13];
  const float* a2  = (const float*)d_in[14];
  float* outp = (float*)d_out;

  const int n = in_sizes[0];  // 262144

  pinn_fused<<<256, 1024, 0, stream>>>(xg, tg, sw, sb, ewp, ebp,
                                       c0, c1, c2, r0, r1, r2, a0, a1, a2,
                                       outp, n);
}